// Round 1
// baseline (442.219 us; speedup 1.0000x reference)
//
#include <hip/hip_runtime.h>
#include <hip/hip_bf16.h>
#include <math.h>

// Problem constants (from reference)
#define B_SZ 32
#define T_SZ 4096
#define DV   512   // DIM_VECT
#define DA   256   // DIM_ATTN
#define DK   512   // DIM_ATTN_BID (matrix feature dim)

typedef __attribute__((ext_vector_type(8))) __bf16 bf16x8;
typedef __attribute__((ext_vector_type(4))) __bf16 bf16x4;
typedef __attribute__((ext_vector_type(4))) float  f32x4;

// Lengths may arrive as int32 or int64 (reference says int64; harness doc says int).
// Valid lengths are in [1, 4096], so for int64 little-endian the high word p[1]==0,
// while for int32 p[1] is a real length >= 1. Probe p[1].
__device__ inline int get_len(const int* __restrict__ p, int b) {
    return (p[1] == 0) ? p[2 * b] : p[b];
}

// ---------------------------------------------------------------------------
// Kernel 0: convert W_mat [DA, DK] f32 -> bf16 (natural [a][k] layout)
// ---------------------------------------------------------------------------
__global__ void conv_wmat_kernel(const float* __restrict__ w, __bf16* __restrict__ out) {
    int i = (blockIdx.x * 256 + threadIdx.x) * 4;
    float4 v = *(const float4*)(w + i);
    bf16x4 o;
    o[0] = (__bf16)v.x; o[1] = (__bf16)v.y; o[2] = (__bf16)v.z; o[3] = (__bf16)v.w;
    *(bf16x4*)(out + i) = o;
}

// ---------------------------------------------------------------------------
// Kernel 1: t1[b,a] = dot(vector[b,:], W_vec[a,:])  (f32), and zero rep area
// ---------------------------------------------------------------------------
__global__ void t1_kernel(const float* __restrict__ vector, const float* __restrict__ wvec,
                          float* __restrict__ t1, float* __restrict__ rep) {
    int b = blockIdx.x, tid = threadIdx.x;
    __shared__ float sv[DV];
    sv[tid]       = vector[b * DV + tid];
    sv[tid + 256] = vector[b * DV + tid + 256];
    rep[b * DV + tid]       = 0.f;
    rep[b * DV + tid + 256] = 0.f;
    __syncthreads();
    const float4* w  = (const float4*)(wvec + (size_t)tid * DV);
    const float4* s4 = (const float4*)sv;
    float acc = 0.f;
#pragma unroll 8
    for (int k = 0; k < DV / 4; k++) {
        float4 wv = w[k]; float4 xv = s4[k];
        acc += wv.x * xv.x + wv.y * xv.y + wv.z * xv.z + wv.w * xv.w;
    }
    t1[b * DA + tid] = acc;
}

// ---------------------------------------------------------------------------
// Kernel 2: fused  logits[b,t] = sum_a W_attn[a] * relu(t1[b,a] + matrix[b,t,:]·W_mat[a,:])
// Tile: 64 t-rows x 256 a-cols per block, 4 waves (each wave: 64t x 64a).
// bf16 MFMA 16x16x32, f32 accumulate. matrix converted f32->bf16 during staging.
// ---------------------------------------------------------------------------
#define TM  64
#define BK  32
#define LDT 40   // padded LDS row stride (bf16 elems); 80B = 16B-aligned, 20-bank step

__global__ __launch_bounds__(256) void logits_kernel(
    const float* __restrict__ matrix, const __bf16* __restrict__ wmat,
    const float* __restrict__ t1, const float* __restrict__ wattn,
    const int* __restrict__ lens, float* __restrict__ logits) {
    int b  = blockIdx.y;
    int t0 = blockIdx.x * TM;
    int len = get_len(lens, b);
    if (t0 >= len) return;   // masked rows never read downstream

    __shared__ __bf16 sA[TM][LDT];
    __shared__ __bf16 sB[DA][LDT];
    __shared__ float s_t1[DA];
    __shared__ float s_wa[DA];
    __shared__ float s_logit[TM];

    int tid = threadIdx.x;
    s_t1[tid] = t1[b * DA + tid];
    s_wa[tid] = wattn[tid];
    if (tid < TM) s_logit[tid] = 0.f;

    int wave = tid >> 6, lane = tid & 63;
    int col = lane & 15;            // A-row / B-col / C-col within 16x16 tile
    int kq  = (lane >> 4) * 8;      // k sub-block

    f32x4 acc[4][4];
    f32x4 zero = {0.f, 0.f, 0.f, 0.f};
#pragma unroll
    for (int i = 0; i < 4; i++)
#pragma unroll
        for (int j = 0; j < 4; j++) acc[i][j] = zero;

    const float*  Ab = matrix + ((size_t)b * T_SZ + t0) * DK;
    const __bf16* Bb = wmat + (size_t)tid * DK;
    int am = tid >> 2;              // 0..63: A row this thread stages
    int ak = (tid & 3) * 8;         // k offset within stage

    for (int k0 = 0; k0 < DK; k0 += BK) {
        __syncthreads();
        // stage A: 8 f32 -> 8 bf16
        float4 a0 = *(const float4*)(Ab + (size_t)am * DK + k0 + ak);
        float4 a1 = *(const float4*)(Ab + (size_t)am * DK + k0 + ak + 4);
        bf16x8 av;
        av[0] = (__bf16)a0.x; av[1] = (__bf16)a0.y; av[2] = (__bf16)a0.z; av[3] = (__bf16)a0.w;
        av[4] = (__bf16)a1.x; av[5] = (__bf16)a1.y; av[6] = (__bf16)a1.z; av[7] = (__bf16)a1.w;
        *(bf16x8*)&sA[am][ak] = av;
        // stage B: 32 bf16 (64B) of W_mat row tid
        const uint4* bsrc = (const uint4*)(Bb + k0);
        uint4 b0 = bsrc[0], b1 = bsrc[1], b2 = bsrc[2], b3 = bsrc[3];
        *(uint4*)&sB[tid][0]  = b0;
        *(uint4*)&sB[tid][8]  = b1;
        *(uint4*)&sB[tid][16] = b2;
        *(uint4*)&sB[tid][24] = b3;
        __syncthreads();

        bf16x8 af[4], bfr[4];
#pragma unroll
        for (int mt = 0; mt < 4; mt++) af[mt]  = *(const bf16x8*)&sA[mt * 16 + col][kq];
#pragma unroll
        for (int nt = 0; nt < 4; nt++) bfr[nt] = *(const bf16x8*)&sB[wave * 64 + nt * 16 + col][kq];
#pragma unroll
        for (int mt = 0; mt < 4; mt++)
#pragma unroll
            for (int nt = 0; nt < 4; nt++)
                acc[mt][nt] = __builtin_amdgcn_mfma_f32_16x16x32_bf16(af[mt], bfr[nt], acc[mt][nt], 0, 0, 0);
    }

    // Epilogue: v = W_attn[a]*relu(t1[a]+t2), reduce over a per t-row.
    // C/D layout: col = lane&15, row = (lane>>4)*4 + reg
    int rg = lane >> 4;
#pragma unroll
    for (int mt = 0; mt < 4; mt++) {
#pragma unroll
        for (int r = 0; r < 4; r++) {
            float v = 0.f;
#pragma unroll
            for (int nt = 0; nt < 4; nt++) {
                int a = wave * 64 + nt * 16 + col;
                float x = acc[mt][nt][r] + s_t1[a];
                v += s_wa[a] * fmaxf(x, 0.f);
            }
            // reduce across the 16 cols (low 4 lane bits; rg preserved)
#pragma unroll
            for (int off = 1; off < 16; off <<= 1) v += __shfl_xor(v, off, 64);
            if (col == 0) atomicAdd(&s_logit[mt * 16 + rg * 4 + r], v);
        }
    }
    __syncthreads();
    if (tid < TM) logits[(size_t)b * T_SZ + t0 + tid] = s_logit[tid];
}

// ---------------------------------------------------------------------------
// Kernel 3: per-row softmax in place (row max is equivalent to global max after
// normalization), masked beyond len (writes zeros there — buffer is poisoned).
// ---------------------------------------------------------------------------
__global__ void softmax_kernel(const int* __restrict__ lens, float* __restrict__ attn) {
    int b = blockIdx.x, tid = threadIdx.x;
    int len = get_len(lens, b);
    float* row = attn + (size_t)b * T_SZ;
    __shared__ float sred[4];

    float m = -1e30f;
    for (int t = tid; t < len; t += 256) m = fmaxf(m, row[t]);
#pragma unroll
    for (int off = 32; off; off >>= 1) m = fmaxf(m, __shfl_xor(m, off, 64));
    if ((tid & 63) == 0) sred[tid >> 6] = m;
    __syncthreads();
    m = fmaxf(fmaxf(sred[0], sred[1]), fmaxf(sred[2], sred[3]));
    __syncthreads();

    float s = 0.f;
    for (int t = tid; t < len; t += 256) s += __expf(row[t] - m);
#pragma unroll
    for (int off = 32; off; off >>= 1) s += __shfl_xor(s, off, 64);
    if ((tid & 63) == 0) sred[tid >> 6] = s;
    __syncthreads();
    s = sred[0] + sred[1] + sred[2] + sred[3];
    float inv = 1.f / s;

    for (int t = tid; t < T_SZ; t += 256) {
        float v = (t < len) ? __expf(row[t] - m) * inv : 0.f;
        row[t] = v;
    }
}

// ---------------------------------------------------------------------------
// Kernel 4: rep[b,d] += sum_t attn[b,t] * matrix[b,t,d], length-clipped chunks,
// atomicAdd into the (pre-zeroed) rep area.
// ---------------------------------------------------------------------------
#define TC 256
__global__ void rep_kernel(const float* __restrict__ matrix, const float* __restrict__ attn,
                           const int* __restrict__ lens, float* __restrict__ rep) {
    int b = blockIdx.y, c = blockIdx.x, tid = threadIdx.x;
    int len = get_len(lens, b);
    int t0 = c * TC;
    if (t0 >= len) return;
    __shared__ float sa[TC];
    sa[tid] = attn[(size_t)b * T_SZ + t0 + tid];
    __syncthreads();
    int n = min(TC, len - t0);
    const float* M = matrix + ((size_t)b * T_SZ + t0) * DK;
    float ax = 0.f, ay = 0.f;
    int d = 2 * tid;
#pragma unroll 4
    for (int t = 0; t < n; t++) {
        float w = sa[t];
        float2 mv = *(const float2*)(M + (size_t)t * DK + d);
        ax = fmaf(w, mv.x, ax);
        ay = fmaf(w, mv.y, ay);
    }
    atomicAdd(&rep[b * DV + d], ax);
    atomicAdd(&rep[b * DV + d + 1], ay);
}

// ---------------------------------------------------------------------------
extern "C" void kernel_launch(void* const* d_in, const int* in_sizes, int n_in,
                              void* d_out, int out_size, void* d_ws, size_t ws_size,
                              hipStream_t stream) {
    const float* vector = (const float*)d_in[0];
    const float* matrix = (const float*)d_in[1];
    const int*   lens   = (const int*)d_in[2];
    const float* wvec   = (const float*)d_in[3];
    const float* wmat   = (const float*)d_in[4];
    const float* wattn  = (const float*)d_in[5];

    float* rep  = (float*)d_out;            // [32, 512]
    float* attn = rep + B_SZ * DV;          // [32, 4096] (used as logits first, then in-place softmax)

    float*  t1      = (float*)d_ws;                          // 32*256 f32 = 32 KB
    __bf16* wmat_bf = (__bf16*)((char*)d_ws + 32768);        // 256*512 bf16 = 256 KB

    conv_wmat_kernel<<<dim3((DA * DK) / (256 * 4)), 256, 0, stream>>>(wmat, wmat_bf);
    t1_kernel<<<dim3(B_SZ), 256, 0, stream>>>(vector, wvec, t1, rep);
    logits_kernel<<<dim3(T_SZ / TM, B_SZ), 256, 0, stream>>>(matrix, wmat_bf, t1, wattn, lens, attn);
    softmax_kernel<<<dim3(B_SZ), 256, 0, stream>>>(lens, attn);
    rep_kernel<<<dim3(T_SZ / TC, B_SZ), 256, 0, stream>>>(matrix, attn, lens, rep);
}